// Round 12
// baseline (211.162 us; speedup 1.0000x reference)
//
#include <hip/hip_runtime.h>
#include <hip/hip_fp8.h>

// GraphSAGE 2-layer inference. N=40000, E=640000, C=128, OUT=121.
// R24 = R23 + CAPX 12->8 with VECTORIZED phase-A slot read. R23 audit:
// phase A's `for(i<mycc) list[..]=sp[i]` has a runtime bound -> compiler
// emits a serial dependent 2B-load loop (~200cyc/iter L2) per (node,region)
// record; 320K records/layer. At CAPX=8 one record = 16B = a single b128
// load + predicated UNROLLED reg->LDS writes (compile-time idx, no scratch).
// Slot region 0.96->0.64 MB/XCD (firmly L2-resident under convert stream).
// Overflow ~80 edges (Poisson(2) tail), exact path; f32 sums of e4m3 values
// are exact -> accumulation-order change is bit-invisible.
// Kept from R23: 16-deep gather, HW fp8 decode/encode, 64-row k_gemm,
// per-XCD-compact cnt/slot, nt stream loads.
// 6 dispatches: memset -> k_main(bucket||convert||prepack) -> agg -> gemm -> agg -> gemm.

#define NCH 128
#define CAPX 8   // per-XCD slots per node (0.64MB/XCD; 16B record = 1 b128 load)
#define EPT 8    // edges per thread in bucket phase

typedef __bf16 bf16x8 __attribute__((ext_vector_type(8)));
typedef float f32x4 __attribute__((ext_vector_type(4)));
typedef float f32x2 __attribute__((ext_vector_type(2)));
typedef unsigned int u32x4 __attribute__((ext_vector_type(4)));
typedef unsigned int u32x2 __attribute__((ext_vector_type(2)));
typedef unsigned short u16x8 __attribute__((ext_vector_type(8)));
// clang-native vectors for nontemporal builtins (HIP_vector_type is a struct -> rejected)
typedef float f32x4v __attribute__((ext_vector_type(4)));

static __device__ __forceinline__ unsigned short f2b(float f) {
  return __builtin_bit_cast(unsigned short, static_cast<__bf16>(f));
}
// HW fp8 e4m3 encode (gfx950: OCP, RNE, saturating) -- single byte
static __device__ __forceinline__ unsigned char f2q_hw(float f) {
  return (unsigned char)(__builtin_amdgcn_cvt_pk_fp8_f32(f, f, 0u, false) & 0xffu);
}

// ---------------- fused main: bucket CSR || x->bf16+fp8 || weight prepack ----------------
// pack[c][t][lane][j] = W'[c*32 + (lane>>4)*8 + j][t*16 + (lane&15)]
// (B-frag for mfma_f32_16x16x32_bf16: n=lane&15, k=(lane>>4)*8+j); W' = [Wl;Wr].
__global__ __launch_bounds__(256) void k_main(
    const int* __restrict__ src, const int* __restrict__ dst, int E,
    int* __restrict__ cntx, unsigned short* __restrict__ slotu,
    int* __restrict__ ovf_n, int2* __restrict__ ovf,
    const float* __restrict__ x, unsigned short* __restrict__ xb,
    unsigned char* __restrict__ x8, int n8,
    const float* __restrict__ W1l, const float* __restrict__ W1r,
    const float* __restrict__ b1l, const float* __restrict__ b1r,
    const float* __restrict__ W2l, const float* __restrict__ W2r,
    const float* __restrict__ b2l, const float* __restrict__ b2r,
    unsigned short* __restrict__ pack1, unsigned short* __restrict__ pack2,
    float* __restrict__ bsum1, float* __restrict__ bsum2, int NOUT,
    int nbBkt, int nbCvt, int Nn) {
  int blk = blockIdx.x;
  if (blk < nbBkt) {  // bucket: 8 edges/thread, XCC-local atomics, compact regions
    unsigned int xcc;
    asm volatile("s_getreg_b32 %0, hwreg(HW_REG_XCC_ID)" : "=s"(xcc));
    xcc &= 7u;
    const long cbase = (long)xcc * Nn;          // cnt region for this XCD
    const long lbase = (long)xcc * Nn * CAPX;   // slot region for this XCD
    const int base = blk * (256 * EPT) + (int)threadIdx.x;
    int d[EPT], s[EPT], pos[EPT];
#pragma unroll
    for (int j = 0; j < EPT; ++j) {
      const int e = base + j * 256;
      const bool ok = e < E;
      d[j] = ok ? __builtin_nontemporal_load(dst + e) : -1;
      s[j] = ok ? __builtin_nontemporal_load(src + e) : 0;
    }
#pragma unroll
    for (int j = 0; j < EPT; ++j) {
      pos[j] = (d[j] >= 0)
          ? __hip_atomic_fetch_add(&cntx[cbase + d[j]], 1,
                                   __ATOMIC_RELAXED, __HIP_MEMORY_SCOPE_WORKGROUP)
          : 0;
    }
#pragma unroll
    for (int j = 0; j < EPT; ++j) {
      if (d[j] >= 0) {
        if (pos[j] < CAPX)
          slotu[lbase + (long)d[j] * CAPX + pos[j]] = (unsigned short)s[j];
        else {
          int o = atomicAdd(ovf_n, 1);  // device-scope, ~80 edges expected
          ovf[o] = make_int2(d[j], s[j]);
        }
      }
    }
    return;
  }
  blk -= nbBkt;
  if (blk < nbCvt) {  // fp32 -> bf16 + fp8 convert, 8 floats/thread (nt LOAD only)
    int i = blk * 256 + threadIdx.x;  // 8-float chunk index
    if (i < n8) {
      const f32x4v va = __builtin_nontemporal_load((const f32x4v*)x + 2 * i);
      const f32x4v vb = __builtin_nontemporal_load((const f32x4v*)x + 2 * i + 1);
      u16x8 r;
      r[0] = f2b(va.x); r[1] = f2b(va.y); r[2] = f2b(va.z); r[3] = f2b(va.w);
      r[4] = f2b(vb.x); r[5] = f2b(vb.y); r[6] = f2b(vb.z); r[7] = f2b(vb.w);
      *((u16x8*)xb + i) = r;
      unsigned int w0 = 0u, w1 = 0u;
      w0 = __builtin_amdgcn_cvt_pk_fp8_f32(va.x, va.y, w0, false);
      w0 = __builtin_amdgcn_cvt_pk_fp8_f32(va.z, va.w, w0, true);
      w1 = __builtin_amdgcn_cvt_pk_fp8_f32(vb.x, vb.y, w1, false);
      w1 = __builtin_amdgcn_cvt_pk_fp8_f32(vb.z, vb.w, w1, true);
      u32x2 u; u[0] = w0; u[1] = w1;
      *((u32x2*)x8 + i) = u;
    }
    return;
  }
  blk -= nbCvt;  // prepack: 32 blocks, 16 per layer
  const int layer = blk >> 4;
  const float* Wl = layer ? W2l : W1l;
  const float* Wr = layer ? W2r : W1r;
  const float* bl = layer ? b2l : b1l;
  const float* br = layer ? b2r : b1r;
  unsigned short* pack = layer ? pack2 : pack1;
  float* bsum = layer ? bsum2 : bsum1;
  const int NO = layer ? NOUT : NCH;
  int tid = (blk & 15) * 256 + threadIdx.x;  // 0..4095
  int c = tid >> 9;
  int t = (tid >> 6) & 7;
  int l = tid & 63;
  int n = t * 16 + (l & 15);
  int kb = c * 32 + ((l >> 4) << 3);
  unsigned short o[8];
#pragma unroll
  for (int j = 0; j < 8; ++j) {
    int k = kb + j;
    float v = 0.f;
    if (n < NO) v = (k < 128) ? Wl[n * 128 + k] : Wr[n * 128 + (k - 128)];
    o[j] = f2b(v);
  }
  ushort4 lo, hi;
  lo.x = o[0]; lo.y = o[1]; lo.z = o[2]; lo.w = o[3];
  hi.x = o[4]; hi.y = o[5]; hi.z = o[6]; hi.w = o[7];
  *(ushort4*)(pack + (long)tid * 8) = lo;
  *(ushort4*)(pack + (long)tid * 8 + 4) = hi;
  if (tid < 128) bsum[tid] = (tid < NO) ? (bl[tid] + br[tid]) : 0.f;
}

// ---------------- mean aggregation (fp8 gather, HW cvt decode, fp32 accum, bf16 out) ----
// Block = 32 groups x 8 lanes; group = one node. Phase A: lane ln loads its
// XCD region's 16B slot record with ONE b128 load, then predicated unrolled
// reg->LDS writes. Phase B: 16-deep uchar16 gather from fp8 rows; decode via
// v_cvt_pk_f32_fp8 -> f32x2 accum. No LDS in the inner loop.
__global__ __launch_bounds__(256) void k_agg(
    const unsigned char* __restrict__ feat8, const int* __restrict__ cntx,
    const unsigned short* __restrict__ slotu, const int* __restrict__ ovf_n,
    const int2* __restrict__ ovf, unsigned short* __restrict__ agg, int N) {
  __shared__ unsigned short list[32][72];   // 64 used; stride 36 words -> distinct banks
  __shared__ int degs[32], ms[32];
  __shared__ int cnts[32][9];               // padded
  const int lg = threadIdx.x >> 3;  // group (node) in block, 0..31
  const int ln = threadIdx.x & 7;   // lane in group, 0..7
  const int g = blockIdx.x * 32 + lg;

  // ---- coalesced cnt read: thread t reads region t>>5, node base+(t&31) ----
  {
    const int xx = threadIdx.x >> 5;
    const int lgg = threadIdx.x & 31;
    const int gg = blockIdx.x * 32 + lgg;
    cnts[lgg][xx] = (gg < N) ? cntx[(long)xx * N + gg] : 0;
  }
  __syncthreads();

  // ---- phase A: build compact index list (lane ln owns XCD region ln) ----
  if (g < N) {
    int deg = 0, p = 0, myoff = 0, mycc = 0;
#pragma unroll
    for (int xx = 0; xx < 8; ++xx) {
      const int cv = cnts[lg][xx];
      const int cc = (cv < CAPX) ? cv : CAPX;
      if (ln == xx) { myoff = p; mycc = cc; }
      p += cc;
      deg += cv;
    }
    if (ln == 0) { degs[lg] = deg; ms[lg] = p; }
    // one 16B load covers the whole CAPX=8 record
    const u16x8 sl = *(const u16x8*)(slotu + ((long)ln * N + g) * CAPX);
#pragma unroll
    for (int i = 0; i < CAPX; ++i)
      if (i < mycc) list[lg][myoff + i] = sl[i];  // compile-time sl index
  } else if (ln == 0) {
    degs[lg] = 0; ms[lg] = 0;
  }
  __syncthreads();

  if (g >= N) return;
  const int m = ms[lg];
  const int col = ln * 16;  // 16 channels per lane
  const unsigned char* fcol = feat8 + col;

  // acc[j] covers channels col+2j, col+2j+1
  f32x2 acc[8];
#pragma unroll
  for (int k = 0; k < 8; ++k) acc[k] = (f32x2){0.f, 0.f};

  // decode one 16B row-slice (4 words); word kq -> channels 4kq..4kq+3.
  // internal index kq (NOT q): callers use q -- macro capture was the R22 bug.
#define ACC_ROW(W)                                                          \
  do {                                                                      \
    _Pragma("unroll")                                                       \
    for (int kq = 0; kq < 4; ++kq) {                                        \
      acc[2 * kq + 0] += __builtin_amdgcn_cvt_pk_f32_fp8((W)[kq], false);   \
      acc[2 * kq + 1] += __builtin_amdgcn_cvt_pk_f32_fp8((W)[kq], true);    \
    }                                                                       \
  } while (0)

  const unsigned short* __restrict__ il = list[lg];
  int j = 0;
  for (; j + 15 < m; j += 16) {  // 16 loads in flight
    u32x4 w[16];
#pragma unroll
    for (int q = 0; q < 16; ++q)
      w[q] = *(const u32x4*)(fcol + (long)il[j + q] * NCH);
#pragma unroll
    for (int q = 0; q < 16; ++q) ACC_ROW(w[q]);
  }
  if (j + 7 < m) {
    u32x4 w[8];
#pragma unroll
    for (int q = 0; q < 8; ++q)
      w[q] = *(const u32x4*)(fcol + (long)il[j + q] * NCH);
#pragma unroll
    for (int q = 0; q < 8; ++q) ACC_ROW(w[q]);
    j += 8;
  }
  if (j + 3 < m) {
    u32x4 w[4];
#pragma unroll
    for (int q = 0; q < 4; ++q)
      w[q] = *(const u32x4*)(fcol + (long)il[j + q] * NCH);
#pragma unroll
    for (int q = 0; q < 4; ++q) ACC_ROW(w[q]);
    j += 4;
  }
  for (; j < m; ++j) {
    const u32x4 w = *(const u32x4*)(fcol + (long)il[j] * NCH);
    ACC_ROW(w);
  }

  // overflow pass (exactness for slots beyond CAPX; ~80 entries expected)
  const int on = *ovf_n;
  for (int o = 0; o < on; ++o) {
    const int2 p = ovf[o];
    if (p.x == g) {
      const u32x4 w = *(const u32x4*)(fcol + (long)p.y * NCH);
      ACC_ROW(w);
    }
  }
#undef ACC_ROW

  const int deg = degs[lg];
  const int dd = (deg < 1) ? 1 : deg;
  const float inv = 1.f / (float)dd;
  u16x8 r0, r1;
#pragma unroll
  for (int k = 0; k < 8; ++k) {
    r0[k] = f2b(acc[k >> 1][k & 1] * inv);           // channels col+0..7
    r1[k] = f2b(acc[4 + (k >> 1)][k & 1] * inv);     // channels col+8..15
  }
  *(u16x8*)(agg + (long)g * NCH + col) = r0;
  *(u16x8*)(agg + (long)g * NCH + col + 8) = r1;
}

// ---------------- MFMA dual-GEMM ----------------
// out[m][n] = relu?( sum_k agg[m][k]Wl[n][k] + self[m][k]Wr[n][k] + bias[n] )
// 64-row blocks: wave w owns rows base+16w (one m-tile), all 8 n-tiles.
// 625 blocks = 2.4/CU for latency hiding. A-frags from global bf16
// (16B/lane), B-frags from prepacked weights (L2-hot, 64KB).
// Layer 1 additionally emits h8 (fp8, HW cvt encode) for the next gather.
__global__ __launch_bounds__(256) void k_gemm(
    const unsigned short* __restrict__ Ag,   // agg  bf16 [M][128]
    const unsigned short* __restrict__ Sf,   // self bf16 [M][128]
    const unsigned short* __restrict__ pack, // [8][8][64][8] bf16
    const float* __restrict__ bsum,          // [128]
    unsigned short* __restrict__ outb,       // bf16 out (layer1) or null
    unsigned char* __restrict__ out8,        // fp8 out (layer1) or null
    float* __restrict__ outf,                // f32 out (layer2) or null
    int M, int NO, int do_relu) {
  const int wave = threadIdx.x >> 6;
  const int lane = threadIdx.x & 63;
  const int R = blockIdx.x * 64 + wave * 16;  // one 16-row m-tile per wave
  const int mrow = lane & 15;
  const int koct = (lane >> 4) * 8;

  int r0 = R + mrow;  if (r0 > M - 1) r0 = M - 1;

  f32x4 acc[8];
#pragma unroll
  for (int t = 0; t < 8; ++t) acc[t] = (f32x4){0.f, 0.f, 0.f, 0.f};

#pragma unroll
  for (int c = 0; c < 8; ++c) {
    const unsigned short* __restrict__ Abase = (c < 4) ? Ag : Sf;
    const int k0 = (c & 3) * 32;
    const bf16x8 a0 = *(const bf16x8*)(Abase + (long)r0 * NCH + k0 + koct);
    const unsigned short* bp = pack + ((long)(c * 8) * 64 + lane) * 8;
#pragma unroll
    for (int t = 0; t < 8; ++t) {
      const bf16x8 bfrag = *(const bf16x8*)(bp + (long)t * 512);
      acc[t] = __builtin_amdgcn_mfma_f32_16x16x32_bf16(a0, bfrag, acc[t], 0, 0, 0);
    }
  }

  // epilogue: C/D layout col=lane&15, row=(lane>>4)*4+reg
  const int nloc = lane & 15;
  const int rquad = (lane >> 4) * 4;
#pragma unroll
  for (int t = 0; t < 8; ++t) {
    const int n = t * 16 + nloc;
    const float bias = bsum[n];
#pragma unroll
    for (int r = 0; r < 4; ++r) {
      const int m = R + rquad + r;
      if (m < M && n < NO) {
        float v = acc[t][r] + bias;
        if (do_relu) v = fmaxf(v, 0.f);
        if (outb) {
          outb[(long)m * NCH + n] = f2b(v);
          out8[(long)m * NCH + n] = f2q_hw(v);
        } else {
          outf[(long)m * NO + n] = v;
        }
      }
    }
  }
}

// ---------------- launch ----------------

extern "C" void kernel_launch(void* const* d_in, const int* in_sizes, int n_in,
                              void* d_out, int out_size, void* d_ws, size_t ws_size,
                              hipStream_t stream) {
  const float* x = (const float*)d_in[0];
  const int* ei = (const int*)d_in[1];
  const float* W1l = (const float*)d_in[2];
  const float* b1l = (const float*)d_in[3];
  const float* W1r = (const float*)d_in[4];
  const float* b1r = (const float*)d_in[5];
  const float* W2l = (const float*)d_in[6];
  const float* b2l = (const float*)d_in[7];
  const float* W2r = (const float*)d_in[8];
  const float* b2r = (const float*)d_in[9];
  float* out = (float*)d_out;

  const int N = in_sizes[0] / NCH;  // 40000
  const int E = in_sizes[1] / 2;    // 640000
  const int NOUT = out_size / N;    // 121

  const int* src = ei;
  const int* dst = ei + E;

  char* w = (char*)d_ws;
  auto alloc = [&](size_t bytes) {
    char* p = w;
    w += (bytes + 255) & ~(size_t)255;
    return p;
  };
  unsigned short* xb = (unsigned short*)alloc((size_t)N * NCH * 2);
  unsigned short* hb = (unsigned short*)alloc((size_t)N * NCH * 2);
  unsigned short* aggb = (unsigned short*)alloc((size_t)N * NCH * 2);
  unsigned char* x8 = (unsigned char*)alloc((size_t)N * NCH);
  unsigned char* h8 = (unsigned char*)alloc((size_t)N * NCH);
  unsigned short* pack1 = (unsigned short*)alloc(8 * 8 * 64 * 8 * 2);
  unsigned short* pack2 = (unsigned short*)alloc(8 * 8 * 64 * 8 * 2);
  float* bsum1 = (float*)alloc(128 * 4);
  float* bsum2 = (float*)alloc(128 * 4);
  int* cntx = (int*)alloc(((size_t)N * 8 + 4) * 4);  // [xcc][node] + ovf_n
  int* ovf_n = cntx + (size_t)N * 8;
  unsigned short* slotu = (unsigned short*)alloc((size_t)N * 8 * CAPX * 2);  // [xcc][node][CAPX]
  int2* ovf = (int2*)alloc((size_t)E * 8);

  const int n8 = N * NCH / 8;
  const int nbBkt = (E + 256 * EPT - 1) / (256 * EPT);  // 313
  const int nbCvt = (n8 + 255) / 256;                   // 2500

  // zero per-XCD degree counters + overflow count
  hipMemsetAsync(cntx, 0, ((size_t)N * 8 + 4) * 4, stream);

  // bucket || convert || prepack in one dispatch
  k_main<<<nbBkt + nbCvt + 32, 256, 0, stream>>>(
      src, dst, E, cntx, slotu, ovf_n, ovf,
      x, xb, x8, n8,
      W1l, W1r, b1l, b1r, W2l, W2r, b2l, b2r,
      pack1, pack2, bsum1, bsum2, NOUT, nbBkt, nbCvt, N);

  const int gaggr = (N + 31) / 32;   // 1250 (32 nodes per 256-thread block)
  const int gblk = (N + 63) / 64;    // 625 (64 rows per block, 16/wave)

  // layer 1 (relu, bf16 + fp8 out)
  k_agg<<<gaggr, 256, 0, stream>>>(x8, cntx, slotu, ovf_n, ovf, aggb, N);
  k_gemm<<<gblk, 256, 0, stream>>>(aggb, xb, pack1, bsum1, hb, h8,
                                   (float*)nullptr, N, NCH, 1);
  // layer 2 (f32 out)
  k_agg<<<gaggr, 256, 0, stream>>>(h8, cntx, slotu, ovf_n, ovf, aggb, N);
  k_gemm<<<gblk, 256, 0, stream>>>(aggb, hb, pack2, bsum2,
                                   (unsigned short*)nullptr, (unsigned char*)nullptr,
                                   out, N, NOUT, 0);
}

// Round 13
// 182.711 us; speedup vs baseline: 1.1557x; 1.1557x over previous
//
#include <hip/hip_runtime.h>
#include <hip/hip_fp8.h>

// GraphSAGE 2-layer inference. N=40000, E=640000, C=128, OUT=121.
// R25 = R24 + O(1) overflow handling. R24's -23us regression mechanism:
// CAPX 12->8 made ovf_n ~90 (was ~0), and the overflow pass is a per-THREAD
// serial 90-iteration dependent-load loop run by every thread of every
// k_agg block (~2-7us serial/wave x ~5 block-generations/CU x 2 layers).
// Fix: cooperative pre-filter -- thread t scans ovf[t::256] (1 coalesced
// load), appends entries for this block's 32 nodes to an LDS list (<=64;
// ~93% of blocks get 0). Groups scan only the LDS list. Exact fallback to
// the full serial scan if >64 relevant entries (never for random input).
// Kept from R24: CAPX=8 single-b128 phase A (16B-aligned), 16-deep gather,
// HW fp8 decode/encode, 64-row k_gemm, per-XCD-compact cnt/slot, nt loads.
// 6 dispatches: memset -> k_main(bucket||convert||prepack) -> agg -> gemm -> agg -> gemm.

#define NCH 128
#define CAPX 8   // per-XCD slots per node (0.64MB/XCD; 16B record = 1 b128 load)
#define EPT 8    // edges per thread in bucket phase
#define OVL_CAP 64  // per-block LDS overflow list capacity

typedef __bf16 bf16x8 __attribute__((ext_vector_type(8)));
typedef float f32x4 __attribute__((ext_vector_type(4)));
typedef float f32x2 __attribute__((ext_vector_type(2)));
typedef unsigned int u32x4 __attribute__((ext_vector_type(4)));
typedef unsigned int u32x2 __attribute__((ext_vector_type(2)));
typedef unsigned short u16x8 __attribute__((ext_vector_type(8)));
// clang-native vectors for nontemporal builtins (HIP_vector_type is a struct -> rejected)
typedef float f32x4v __attribute__((ext_vector_type(4)));

static __device__ __forceinline__ unsigned short f2b(float f) {
  return __builtin_bit_cast(unsigned short, static_cast<__bf16>(f));
}
// HW fp8 e4m3 encode (gfx950: OCP, RNE, saturating) -- single byte
static __device__ __forceinline__ unsigned char f2q_hw(float f) {
  return (unsigned char)(__builtin_amdgcn_cvt_pk_fp8_f32(f, f, 0u, false) & 0xffu);
}

// ---------------- fused main: bucket CSR || x->bf16+fp8 || weight prepack ----------------
// pack[c][t][lane][j] = W'[c*32 + (lane>>4)*8 + j][t*16 + (lane&15)]
// (B-frag for mfma_f32_16x16x32_bf16: n=lane&15, k=(lane>>4)*8+j); W' = [Wl;Wr].
__global__ __launch_bounds__(256) void k_main(
    const int* __restrict__ src, const int* __restrict__ dst, int E,
    int* __restrict__ cntx, unsigned short* __restrict__ slotu,
    int* __restrict__ ovf_n, int2* __restrict__ ovf,
    const float* __restrict__ x, unsigned short* __restrict__ xb,
    unsigned char* __restrict__ x8, int n8,
    const float* __restrict__ W1l, const float* __restrict__ W1r,
    const float* __restrict__ b1l, const float* __restrict__ b1r,
    const float* __restrict__ W2l, const float* __restrict__ W2r,
    const float* __restrict__ b2l, const float* __restrict__ b2r,
    unsigned short* __restrict__ pack1, unsigned short* __restrict__ pack2,
    float* __restrict__ bsum1, float* __restrict__ bsum2, int NOUT,
    int nbBkt, int nbCvt, int Nn) {
  int blk = blockIdx.x;
  if (blk < nbBkt) {  // bucket: 8 edges/thread, XCC-local atomics, compact regions
    unsigned int xcc;
    asm volatile("s_getreg_b32 %0, hwreg(HW_REG_XCC_ID)" : "=s"(xcc));
    xcc &= 7u;
    const long cbase = (long)xcc * Nn;          // cnt region for this XCD
    const long lbase = (long)xcc * Nn * CAPX;   // slot region for this XCD
    const int base = blk * (256 * EPT) + (int)threadIdx.x;
    int d[EPT], s[EPT], pos[EPT];
#pragma unroll
    for (int j = 0; j < EPT; ++j) {
      const int e = base + j * 256;
      const bool ok = e < E;
      d[j] = ok ? __builtin_nontemporal_load(dst + e) : -1;
      s[j] = ok ? __builtin_nontemporal_load(src + e) : 0;
    }
#pragma unroll
    for (int j = 0; j < EPT; ++j) {
      pos[j] = (d[j] >= 0)
          ? __hip_atomic_fetch_add(&cntx[cbase + d[j]], 1,
                                   __ATOMIC_RELAXED, __HIP_MEMORY_SCOPE_WORKGROUP)
          : 0;
    }
#pragma unroll
    for (int j = 0; j < EPT; ++j) {
      if (d[j] >= 0) {
        if (pos[j] < CAPX)
          slotu[lbase + (long)d[j] * CAPX + pos[j]] = (unsigned short)s[j];
        else {
          int o = atomicAdd(ovf_n, 1);  // device-scope, ~90 edges expected
          ovf[o] = make_int2(d[j], s[j]);
        }
      }
    }
    return;
  }
  blk -= nbBkt;
  if (blk < nbCvt) {  // fp32 -> bf16 + fp8 convert, 8 floats/thread (nt LOAD only)
    int i = blk * 256 + threadIdx.x;  // 8-float chunk index
    if (i < n8) {
      const f32x4v va = __builtin_nontemporal_load((const f32x4v*)x + 2 * i);
      const f32x4v vb = __builtin_nontemporal_load((const f32x4v*)x + 2 * i + 1);
      u16x8 r;
      r[0] = f2b(va.x); r[1] = f2b(va.y); r[2] = f2b(va.z); r[3] = f2b(va.w);
      r[4] = f2b(vb.x); r[5] = f2b(vb.y); r[6] = f2b(vb.z); r[7] = f2b(vb.w);
      *((u16x8*)xb + i) = r;
      unsigned int w0 = 0u, w1 = 0u;
      w0 = __builtin_amdgcn_cvt_pk_fp8_f32(va.x, va.y, w0, false);
      w0 = __builtin_amdgcn_cvt_pk_fp8_f32(va.z, va.w, w0, true);
      w1 = __builtin_amdgcn_cvt_pk_fp8_f32(vb.x, vb.y, w1, false);
      w1 = __builtin_amdgcn_cvt_pk_fp8_f32(vb.z, vb.w, w1, true);
      u32x2 u; u[0] = w0; u[1] = w1;
      *((u32x2*)x8 + i) = u;
    }
    return;
  }
  blk -= nbCvt;  // prepack: 32 blocks, 16 per layer
  const int layer = blk >> 4;
  const float* Wl = layer ? W2l : W1l;
  const float* Wr = layer ? W2r : W1r;
  const float* bl = layer ? b2l : b1l;
  const float* br = layer ? b2r : b1r;
  unsigned short* pack = layer ? pack2 : pack1;
  float* bsum = layer ? bsum2 : bsum1;
  const int NO = layer ? NOUT : NCH;
  int tid = (blk & 15) * 256 + threadIdx.x;  // 0..4095
  int c = tid >> 9;
  int t = (tid >> 6) & 7;
  int l = tid & 63;
  int n = t * 16 + (l & 15);
  int kb = c * 32 + ((l >> 4) << 3);
  unsigned short o[8];
#pragma unroll
  for (int j = 0; j < 8; ++j) {
    int k = kb + j;
    float v = 0.f;
    if (n < NO) v = (k < 128) ? Wl[n * 128 + k] : Wr[n * 128 + (k - 128)];
    o[j] = f2b(v);
  }
  ushort4 lo, hi;
  lo.x = o[0]; lo.y = o[1]; lo.z = o[2]; lo.w = o[3];
  hi.x = o[4]; hi.y = o[5]; hi.z = o[6]; hi.w = o[7];
  *(ushort4*)(pack + (long)tid * 8) = lo;
  *(ushort4*)(pack + (long)tid * 8 + 4) = hi;
  if (tid < 128) bsum[tid] = (tid < NO) ? (bl[tid] + br[tid]) : 0.f;
}

// ---------------- mean aggregation (fp8 gather, HW cvt decode, fp32 accum, bf16 out) ----
// Block = 32 groups x 8 lanes; group = one node. Phase A: lane ln loads its
// XCD region's 16B slot record with ONE b128 load + predicated unrolled
// reg->LDS writes; in parallel, all 256 threads pre-filter the global
// overflow list into an LDS list for this block's 32 nodes (1 coalesced
// load per thread; ~93% of blocks get 0 entries). Phase B: 16-deep uchar16
// gather, HW cvt decode, f32x2 accum; overflow from the tiny LDS list.
__global__ __launch_bounds__(256) void k_agg(
    const unsigned char* __restrict__ feat8, const int* __restrict__ cntx,
    const unsigned short* __restrict__ slotu, const int* __restrict__ ovf_n,
    const int2* __restrict__ ovf, unsigned short* __restrict__ agg, int N) {
  __shared__ unsigned short list[32][72];   // 64 used; stride 36 words -> distinct banks
  __shared__ int degs[32], ms[32];
  __shared__ int cnts[32][9];               // padded
  __shared__ int2 ovl[OVL_CAP];             // block-relevant overflow entries
  __shared__ int ovl_n, ovl_fb;
  const int lg = threadIdx.x >> 3;  // group (node) in block, 0..31
  const int ln = threadIdx.x & 7;   // lane in group, 0..7
  const int g = blockIdx.x * 32 + lg;

  if (threadIdx.x == 0) { ovl_n = 0; ovl_fb = 0; }

  // ---- coalesced cnt read: thread t reads region t>>5, node base+(t&31) ----
  {
    const int xx = threadIdx.x >> 5;
    const int lgg = threadIdx.x & 31;
    const int gg = blockIdx.x * 32 + lgg;
    cnts[lgg][xx] = (gg < N) ? cntx[(long)xx * N + gg] : 0;
  }
  __syncthreads();

  // ---- overflow pre-filter: thread t scans ovf[t::256] (usually 1 iter) ----
  const int on = *ovf_n;
  {
    const int lo = blockIdx.x * 32, hi = lo + 32;
    for (int o = threadIdx.x; o < on; o += 256) {
      const int2 p = ovf[o];
      if (p.x >= lo && p.x < hi) {
        const int idx = atomicAdd(&ovl_n, 1);
        if (idx < OVL_CAP) ovl[idx] = p;
        else ovl_fb = 1;  // exact fallback path below
      }
    }
  }

  // ---- phase A: build compact index list (lane ln owns XCD region ln) ----
  if (g < N) {
    int deg = 0, p = 0, myoff = 0, mycc = 0;
#pragma unroll
    for (int xx = 0; xx < 8; ++xx) {
      const int cv = cnts[lg][xx];
      const int cc = (cv < CAPX) ? cv : CAPX;
      if (ln == xx) { myoff = p; mycc = cc; }
      p += cc;
      deg += cv;
    }
    if (ln == 0) { degs[lg] = deg; ms[lg] = p; }
    // one 16B load covers the whole CAPX=8 record
    const u16x8 sl = *(const u16x8*)(slotu + ((long)ln * N + g) * CAPX);
#pragma unroll
    for (int i = 0; i < CAPX; ++i)
      if (i < mycc) list[lg][myoff + i] = sl[i];  // compile-time sl index
  } else if (ln == 0) {
    degs[lg] = 0; ms[lg] = 0;
  }
  __syncthreads();

  if (g >= N) return;
  const int m = ms[lg];
  const int col = ln * 16;  // 16 channels per lane
  const unsigned char* fcol = feat8 + col;

  // acc[j] covers channels col+2j, col+2j+1
  f32x2 acc[8];
#pragma unroll
  for (int k = 0; k < 8; ++k) acc[k] = (f32x2){0.f, 0.f};

  // decode one 16B row-slice (4 words); word kq -> channels 4kq..4kq+3.
  // internal index kq (NOT q): callers use q -- macro capture was the R22 bug.
#define ACC_ROW(W)                                                          \
  do {                                                                      \
    _Pragma("unroll")                                                       \
    for (int kq = 0; kq < 4; ++kq) {                                        \
      acc[2 * kq + 0] += __builtin_amdgcn_cvt_pk_f32_fp8((W)[kq], false);   \
      acc[2 * kq + 1] += __builtin_amdgcn_cvt_pk_f32_fp8((W)[kq], true);    \
    }                                                                       \
  } while (0)

  const unsigned short* __restrict__ il = list[lg];
  int j = 0;
  for (; j + 15 < m; j += 16) {  // 16 loads in flight
    u32x4 w[16];
#pragma unroll
    for (int q = 0; q < 16; ++q)
      w[q] = *(const u32x4*)(fcol + (long)il[j + q] * NCH);
#pragma unroll
    for (int q = 0; q < 16; ++q) ACC_ROW(w[q]);
  }
  if (j + 7 < m) {
    u32x4 w[8];
#pragma unroll
    for (int q = 0; q < 8; ++q)
      w[q] = *(const u32x4*)(fcol + (long)il[j + q] * NCH);
#pragma unroll
    for (int q = 0; q < 8; ++q) ACC_ROW(w[q]);
    j += 8;
  }
  if (j + 3 < m) {
    u32x4 w[4];
#pragma unroll
    for (int q = 0; q < 4; ++q)
      w[q] = *(const u32x4*)(fcol + (long)il[j + q] * NCH);
#pragma unroll
    for (int q = 0; q < 4; ++q) ACC_ROW(w[q]);
    j += 4;
  }
  for (; j < m; ++j) {
    const u32x4 w = *(const u32x4*)(fcol + (long)il[j] * NCH);
    ACC_ROW(w);
  }

  // overflow: LDS-filtered list (typically empty); exact serial fallback if
  // the list overflowed (adversarial inputs only).
  if (!ovl_fb) {
    const int onl = ovl_n;
    for (int o = 0; o < onl; ++o) {
      const int2 p = ovl[o];
      if (p.x == g) {
        const u32x4 w = *(const u32x4*)(fcol + (long)p.y * NCH);
        ACC_ROW(w);
      }
    }
  } else {
    for (int o = 0; o < on; ++o) {
      const int2 p = ovf[o];
      if (p.x == g) {
        const u32x4 w = *(const u32x4*)(fcol + (long)p.y * NCH);
        ACC_ROW(w);
      }
    }
  }
#undef ACC_ROW

  const int deg = degs[lg];
  const int dd = (deg < 1) ? 1 : deg;
  const float inv = 1.f / (float)dd;
  u16x8 r0, r1;
#pragma unroll
  for (int k = 0; k < 8; ++k) {
    r0[k] = f2b(acc[k >> 1][k & 1] * inv);           // channels col+0..7
    r1[k] = f2b(acc[4 + (k >> 1)][k & 1] * inv);     // channels col+8..15
  }
  *(u16x8*)(agg + (long)g * NCH + col) = r0;
  *(u16x8*)(agg + (long)g * NCH + col + 8) = r1;
}

// ---------------- MFMA dual-GEMM ----------------
// out[m][n] = relu?( sum_k agg[m][k]Wl[n][k] + self[m][k]Wr[n][k] + bias[n] )
// 64-row blocks: wave w owns rows base+16w (one m-tile), all 8 n-tiles.
// 625 blocks = 2.4/CU for latency hiding. A-frags from global bf16
// (16B/lane), B-frags from prepacked weights (L2-hot, 64KB).
// Layer 1 additionally emits h8 (fp8, HW cvt encode) for the next gather.
__global__ __launch_bounds__(256) void k_gemm(
    const unsigned short* __restrict__ Ag,   // agg  bf16 [M][128]
    const unsigned short* __restrict__ Sf,   // self bf16 [M][128]
    const unsigned short* __restrict__ pack, // [8][8][64][8] bf16
    const float* __restrict__ bsum,          // [128]
    unsigned short* __restrict__ outb,       // bf16 out (layer1) or null
    unsigned char* __restrict__ out8,        // fp8 out (layer1) or null
    float* __restrict__ outf,                // f32 out (layer2) or null
    int M, int NO, int do_relu) {
  const int wave = threadIdx.x >> 6;
  const int lane = threadIdx.x & 63;
  const int R = blockIdx.x * 64 + wave * 16;  // one 16-row m-tile per wave
  const int mrow = lane & 15;
  const int koct = (lane >> 4) * 8;

  int r0 = R + mrow;  if (r0 > M - 1) r0 = M - 1;

  f32x4 acc[8];
#pragma unroll
  for (int t = 0; t < 8; ++t) acc[t] = (f32x4){0.f, 0.f, 0.f, 0.f};

#pragma unroll
  for (int c = 0; c < 8; ++c) {
    const unsigned short* __restrict__ Abase = (c < 4) ? Ag : Sf;
    const int k0 = (c & 3) * 32;
    const bf16x8 a0 = *(const bf16x8*)(Abase + (long)r0 * NCH + k0 + koct);
    const unsigned short* bp = pack + ((long)(c * 8) * 64 + lane) * 8;
#pragma unroll
    for (int t = 0; t < 8; ++t) {
      const bf16x8 bfrag = *(const bf16x8*)(bp + (long)t * 512);
      acc[t] = __builtin_amdgcn_mfma_f32_16x16x32_bf16(a0, bfrag, acc[t], 0, 0, 0);
    }
  }

  // epilogue: C/D layout col=lane&15, row=(lane>>4)*4+reg
  const int nloc = lane & 15;
  const int rquad = (lane >> 4) * 4;
#pragma unroll
  for (int t = 0; t < 8; ++t) {
    const int n = t * 16 + nloc;
    const float bias = bsum[n];
#pragma unroll
    for (int r = 0; r < 4; ++r) {
      const int m = R + rquad + r;
      if (m < M && n < NO) {
        float v = acc[t][r] + bias;
        if (do_relu) v = fmaxf(v, 0.f);
        if (outb) {
          outb[(long)m * NCH + n] = f2b(v);
          out8[(long)m * NCH + n] = f2q_hw(v);
        } else {
          outf[(long)m * NO + n] = v;
        }
      }
    }
  }
}

// ---------------- launch ----------------

extern "C" void kernel_launch(void* const* d_in, const int* in_sizes, int n_in,
                              void* d_out, int out_size, void* d_ws, size_t ws_size,
                              hipStream_t stream) {
  const float* x = (const float*)d_in[0];
  const int* ei = (const int*)d_in[1];
  const float* W1l = (const float*)d_in[2];
  const float* b1l = (const float*)d_in[3];
  const float* W1r = (const float*)d_in[4];
  const float* b1r = (const float*)d_in[5];
  const float* W2l = (const float*)d_in[6];
  const float* b2l = (const float*)d_in[7];
  const float* W2r = (const float*)d_in[8];
  const float* b2r = (const float*)d_in[9];
  float* out = (float*)d_out;

  const int N = in_sizes[0] / NCH;  // 40000
  const int E = in_sizes[1] / 2;    // 640000
  const int NOUT = out_size / N;    // 121

  const int* src = ei;
  const int* dst = ei + E;

  char* w = (char*)d_ws;
  auto alloc = [&](size_t bytes) {
    char* p = w;
    w += (bytes + 255) & ~(size_t)255;
    return p;
  };
  unsigned short* xb = (unsigned short*)alloc((size_t)N * NCH * 2);
  unsigned short* hb = (unsigned short*)alloc((size_t)N * NCH * 2);
  unsigned short* aggb = (unsigned short*)alloc((size_t)N * NCH * 2);
  unsigned char* x8 = (unsigned char*)alloc((size_t)N * NCH);
  unsigned char* h8 = (unsigned char*)alloc((size_t)N * NCH);
  unsigned short* pack1 = (unsigned short*)alloc(8 * 8 * 64 * 8 * 2);
  unsigned short* pack2 = (unsigned short*)alloc(8 * 8 * 64 * 8 * 2);
  float* bsum1 = (float*)alloc(128 * 4);
  float* bsum2 = (float*)alloc(128 * 4);
  int* cntx = (int*)alloc(((size_t)N * 8 + 4) * 4);  // [xcc][node] + ovf_n
  int* ovf_n = cntx + (size_t)N * 8;
  unsigned short* slotu = (unsigned short*)alloc((size_t)N * 8 * CAPX * 2);  // [xcc][node][CAPX]
  int2* ovf = (int2*)alloc((size_t)E * 8);

  const int n8 = N * NCH / 8;
  const int nbBkt = (E + 256 * EPT - 1) / (256 * EPT);  // 313
  const int nbCvt = (n8 + 255) / 256;                   // 2500

  // zero per-XCD degree counters + overflow count
  hipMemsetAsync(cntx, 0, ((size_t)N * 8 + 4) * 4, stream);

  // bucket || convert || prepack in one dispatch
  k_main<<<nbBkt + nbCvt + 32, 256, 0, stream>>>(
      src, dst, E, cntx, slotu, ovf_n, ovf,
      x, xb, x8, n8,
      W1l, W1r, b1l, b1r, W2l, W2r, b2l, b2r,
      pack1, pack2, bsum1, bsum2, NOUT, nbBkt, nbCvt, N);

  const int gaggr = (N + 31) / 32;   // 1250 (32 nodes per 256-thread block)
  const int gblk = (N + 63) / 64;    // 625 (64 rows per block, 16/wave)

  // layer 1 (relu, bf16 + fp8 out)
  k_agg<<<gaggr, 256, 0, stream>>>(x8, cntx, slotu, ovf_n, ovf, aggb, N);
  k_gemm<<<gblk, 256, 0, stream>>>(aggb, xb, pack1, bsum1, hb, h8,
                                   (float*)nullptr, N, NCH, 1);
  // layer 2 (f32 out)
  k_agg<<<gaggr, 256, 0, stream>>>(h8, cntx, slotu, ovf_n, ovf, aggb, N);
  k_gemm<<<gblk, 256, 0, stream>>>(aggb, hb, pack2, bsum2,
                                   (unsigned short*)nullptr, (unsigned char*)nullptr,
                                   out, N, NOUT, 0);
}